// Round 19
// baseline (43.191 us; speedup 1.0000x reference)
//
#include <hip/hip_runtime.h>
#include <hip/hip_bf16.h>
#include <math.h>

#define NPTS   262144
#define UNITS  256
#define STR    15          // rect row stride in prep power-build (deg<=14)
#define NCO    225         // 15*15 rect slots per unit-net build
#define LSTR   16          // padded output row stride (float4-exact)
#define OFF_PU 0           // pred u: rows 0..12 -> 13*16 = 208
#define OFF_LU 208         // lap  u: rows 0..14 -> 15*16 = 240
#define OFF_PV 448
#define OFF_LV 656
#define CFTOT  896         // total padded coefficient floats
#define PBLK   128         // prep blocks (4 waves each, ONE (j,net) per wave)
#define PPT    4           // points per thread in main
#define MTPB   256
#define MBLK   256         // main blocks; MBLK*MTPB*PPT == NPTS
#define QSTRIDE 65536      // point stride between a thread's 4 points

// deg-6 Taylor of e^-t about t=1.1 (monomial coeffs); |err| <= 4e-4 on t in [-0.2,2.4]
__device__ __constant__ float CC[8] = {
    0.99985117f, -0.99903214f, 0.49728235f, -0.16237637f,
    0.03751734f, -0.00582524f, 0.00046232f, 0.0f };

// ---------------------------------------------------------------------------
// prep: wave w of block bid owns task id = bid*4+w -> unit j = id>>1,
// net = id&1. ONE 7-iteration power-conv per wave, one staging pass.
// Block 0 also zeroes main's last-block counter (stream-ordered before main).
// ---------------------------------------------------------------------------
__global__ __launch_bounds__(256) void rbf_prep(
    const float* __restrict__ mu_u, const float* __restrict__ beta_u,
    const float* __restrict__ W_u,
    const float* __restrict__ mu_v, const float* __restrict__ beta_v,
    const float* __restrict__ W_v,
    float* __restrict__ partial, int* __restrict__ flagBlk,
    unsigned* __restrict__ cntMain)
{
    const int tid  = threadIdx.x;
    const int bid  = blockIdx.x;
    const int w    = tid >> 6;
    const int lane = tid & 63;
    const int id   = bid * 4 + w;          // 0..511
    const int j    = id >> 1;              // unit
    const int net  = id & 1;               // 0 = u, 1 = v

    if (bid == 0 && tid == 0) *cntMain = 0u;   // re-zero every call

    __shared__ float pwA[4][NCO];
    __shared__ float pwB[4][NCO];
    __shared__ int   sflag[4];

    int cidx[4], gi[4], gm[4];
    #pragma unroll
    for (int r = 0; r < 4; ++r) {
        const int c = lane + 64 * r;
        cidx[r] = c;
        gi[r]   = c / STR;
        gm[r]   = c - STR * gi[r];
    }

    const float* mu = net ? mu_v   : mu_u;
    const float* be = net ? beta_v : beta_u;
    const float* W  = net ? W_v    : W_u;
    const float mx  = mu[j], my = mu[UNITS + j];
    const float b   = be[j], wgt = W[j];

    // validity of deg-6 approx over safety box [-0.05,1.05]^2
    const float xlo = -0.05f, xhi = 1.05f;
    const float dxl = xlo - mx, dxh = xhi - mx;
    const float dyl = xlo - my, dyh = xhi - my;
    const float dx2max = fmaxf(dxl*dxl, dxh*dxh);
    const float dy2max = fmaxf(dyl*dyl, dyh*dyh);
    const float dx2min = (dxl <= 0.f && dxh >= 0.f) ? 0.f : fminf(dxl*dxl, dxh*dxh);
    const float dy2min = (dyl <= 0.f && dyh >= 0.f) ? 0.f : fminf(dyl*dyl, dyh*dyh);
    const float t1 = b * (dx2min + dy2min);
    const float t2 = b * (dx2max + dy2max);
    const float tlo = fminf(t1, t2), thi = fmaxf(t1, t2);
    const int bad = !(thi <= 2.4f && tlo >= -0.2f);
    if (lane == 0) sflag[w] = bad;

    // quadratic t(X,Y), X = x-0.5, Y = y-0.5
    const float ax = mx - 0.5f, ay = my - 0.5f;
    const float qXX = b, qYY = b;
    const float qX = -2.f*b*ax, qY = -2.f*b*ay;
    const float q0 = b*(ax*ax + ay*ay);

    const float fourwb = 4.f * wgt * b;
    float cP[8], cL[8];
    #pragma unroll
    for (int m = 0; m < 8; ++m) {
        cP[m] = wgt * CC[m];
        cL[m] = fourwb * ((m ? CC[m-1] : 0.f) - CC[m]);
    }

    float* A = &pwA[w][0];
    float* B = &pwB[w][0];
    #pragma unroll
    for (int r = 0; r < 4; ++r) {
        const int c = cidx[r];
        if (c < NCO) {
            float v = 0.f;
            if (c == 0)          v = q0;
            else if (c == 1)     v = qY;
            else if (c == 2)     v = qYY;
            else if (c == STR)   v = qX;
            else if (c == 2*STR) v = qXX;
            A[c] = v;
        }
    }
    __threadfence_block();

    float aP[4] = {0,0,0,0}, aL[4] = {0,0,0,0};
    #pragma unroll
    for (int r = 0; r < 4; ++r)
        if (cidx[r] == 0) { aP[r] = cP[0]; aL[r] = cL[0]; }

    #pragma unroll
    for (int m = 1; m <= 7; ++m) {
        #pragma unroll
        for (int r = 0; r < 4; ++r) {
            const int c = cidx[r];
            if (c < NCO) {
                const float p = A[c];
                aP[r] = fmaf(cP[m], p, aP[r]);
                aL[r] = fmaf(cL[m], p, aL[r]);
            }
        }
        if (m < 7) {
            #pragma unroll
            for (int r = 0; r < 4; ++r) {
                const int c = cidx[r];
                if (c < NCO) {
                    float acc = q0 * A[c];
                    if (gm[r] >= 1) acc = fmaf(qY,  A[c-1],     acc);
                    if (gm[r] >= 2) acc = fmaf(qYY, A[c-2],     acc);
                    if (gi[r] >= 1) acc = fmaf(qX,  A[c-STR],   acc);
                    if (gi[r] >= 2) acc = fmaf(qXX, A[c-2*STR], acc);
                    B[c] = acc;
                }
            }
            float* T = A; A = B; B = T;
            __threadfence_block();
        }
    }

    // ---- stage per-wave accs, single combined write pass ----
    __syncthreads();
    #pragma unroll
    for (int r = 0; r < 4; ++r) {
        const int c = cidx[r];
        if (c < NCO) { pwA[w][c] = aP[r]; pwB[w][c] = aL[r]; }
    }
    __syncthreads();
    {
        float* dst = partial + bid * CFTOT;
        #pragma unroll
        for (int k = 0; k < 4; ++k) {
            const int c = tid + 256 * k;
            if (c < CFTOT) {
                float v = 0.f;
                int idx, isLap, nsel;
                if (c < 208)      { idx = c;       isLap = 0; nsel = 0; }
                else if (c < 448) { idx = c - 208; isLap = 1; nsel = 0; }
                else if (c < 656) { idx = c - 448; isLap = 0; nsel = 1; }
                else              { idx = c - 656; isLap = 1; nsel = 1; }
                const int i = idx >> 4, m = idx & 15;
                if (m < 15) {
                    const int cs = i * STR + m;
                    if (!isLap) v = pwA[nsel][cs] + pwA[2 + nsel][cs];
                    else        v = pwB[nsel][cs] + pwB[2 + nsel][cs];
                }
                dst[c] = v;
            }
        }
    }
    if (tid == 0)
        flagBlk[bid] = sflag[0] | sflag[1] | sflag[2] | sflag[3];
}

// ---------------------------------------------------------------------------
// fold: 128 block-partials -> coefF (fixed order) + flagAll. 4 blocks.
// ---------------------------------------------------------------------------
__global__ __launch_bounds__(256) void rbf_fold(
    const float* __restrict__ partial, const int* __restrict__ flagBlk,
    float* __restrict__ coefF, int* __restrict__ flagAll)
{
    const int tid = threadIdx.x;
    const int c   = blockIdx.x * 256 + tid;
    if (c < CFTOT) {
        float s = 0.f;
        #pragma unroll 8
        for (int p = 0; p < PBLK; ++p)
            s += partial[p * CFTOT + c];
        coefF[c] = s;
    }
    if (blockIdx.x == 0 && tid < 128) {
        int f = flagBlk[tid];
        for (int off = 32; off > 0; off >>= 1)
            f |= __shfl_down(f, off);
        __shared__ int ff[2];
        if ((tid & 63) == 0) ff[tid >> 6] = f;
        __syncthreads();
        if (tid == 0) *flagAll = ff[0] | ff[1];
    }
}

// ---------------------------------------------------------------------------
// eval4: padded (stride-16) bivariate poly, total degree D, at 4 points.
// One ds_read_b128 (uniform broadcast) feeds 16 FMAs; 4 independent
// Horner chains hide LDS latency at 1 wave/SIMD. (R17-proven)
// ---------------------------------------------------------------------------
template<int D>
__device__ __forceinline__ void eval4(const float* sco,
    float X0, float X1, float X2, float X3,
    float Y0, float Y1, float Y2, float Y3,
    float& h0, float& h1, float& h2, float& h3)
{
    h0 = h1 = h2 = h3 = 0.f;
    #pragma unroll
    for (int ii = 0; ii <= D; ++ii) {
        const int i = D - ii;                 // row, high X-degree first
        const int K = (D - i + 4) / 4;        // quads needed in this row
        float r0 = 0.f, r1 = 0.f, r2 = 0.f, r3 = 0.f;
        #pragma unroll
        for (int kk = 0; kk < K; ++kk) {
            const int k = K - 1 - kk;
            const float4 q = *(const float4*)(sco + i*LSTR + 4*k);
            r0 = fmaf(r0, Y0, q.w); r1 = fmaf(r1, Y1, q.w);
            r2 = fmaf(r2, Y2, q.w); r3 = fmaf(r3, Y3, q.w);
            r0 = fmaf(r0, Y0, q.z); r1 = fmaf(r1, Y1, q.z);
            r2 = fmaf(r2, Y2, q.z); r3 = fmaf(r3, Y3, q.z);
            r0 = fmaf(r0, Y0, q.y); r1 = fmaf(r1, Y1, q.y);
            r2 = fmaf(r2, Y2, q.y); r3 = fmaf(r3, Y3, q.y);
            r0 = fmaf(r0, Y0, q.x); r1 = fmaf(r1, Y1, q.x);
            r2 = fmaf(r2, Y2, q.x); r3 = fmaf(r3, Y3, q.x);
        }
        h0 = fmaf(h0, X0, r0); h1 = fmaf(h1, X1, r1);
        h2 = fmaf(h2, X2, r2); h3 = fmaf(h3, X3, r3);
    }
}

__global__ __launch_bounds__(MTPB) void rbf_main(
    const float* __restrict__ gx, const float* __restrict__ gy,
    const float* __restrict__ gu, const float* __restrict__ gv,
    const float* __restrict__ gdu, const float* __restrict__ gdv,
    const float* __restrict__ coefF, const int* __restrict__ flagAll,
    const float* __restrict__ mu_u, const float* __restrict__ beta_u,
    const float* __restrict__ W_u,
    const float* __restrict__ mu_v, const float* __restrict__ beta_v,
    const float* __restrict__ W_v,
    const float* __restrict__ p_d, const float* __restrict__ p_a,
    const float* __restrict__ p_b, const float* __restrict__ p_um,
    const float* __restrict__ p_vm, const float* __restrict__ p_us,
    const float* __restrict__ p_vs,
    float* __restrict__ part, float* __restrict__ out,
    unsigned* __restrict__ cnt)
{
    const int tid = threadIdx.x;
    const int bid = blockIdx.x;
    const int i0  = bid * MTPB + tid;

    __shared__ __align__(16) float sco[CFTOT];  // 3.6 KB coef table
    __shared__ float red[4][6];
    __shared__ int amLast;
    if (tid < CFTOT/4)
        ((float4*)sco)[tid] = ((const float4*)coefF)[tid];
    __syncthreads();

    float xs[PPT], ys[PPT];
    #pragma unroll
    for (int p = 0; p < PPT; ++p) {
        xs[p] = gx[i0 + p*QSTRIDE];
        ys[p] = gy[i0 + p*QSTRIDE];
    }

    const int bad = __builtin_amdgcn_readfirstlane(*flagAll);
    bool in = true;
    #pragma unroll
    for (int p = 0; p < PPT; ++p)
        in = in && (xs[p] >= -0.05f) && (xs[p] <= 1.05f)
                && (ys[p] >= -0.05f) && (ys[p] <= 1.05f);
    const bool allIn = __all(in);

    float up[PPT], vp[PPT], lu[PPT], lv[PPT];
    if (!bad && allIn) {
        const float X0 = xs[0]-0.5f, X1 = xs[1]-0.5f, X2 = xs[2]-0.5f, X3 = xs[3]-0.5f;
        const float Y0 = ys[0]-0.5f, Y1 = ys[1]-0.5f, Y2 = ys[2]-0.5f, Y3 = ys[3]-0.5f;
        eval4<12>(sco + OFF_PU, X0,X1,X2,X3, Y0,Y1,Y2,Y3, up[0],up[1],up[2],up[3]);
        eval4<14>(sco + OFF_LU, X0,X1,X2,X3, Y0,Y1,Y2,Y3, lu[0],lu[1],lu[2],lu[3]);
        eval4<12>(sco + OFF_PV, X0,X1,X2,X3, Y0,Y1,Y2,Y3, vp[0],vp[1],vp[2],vp[3]);
        eval4<14>(sco + OFF_LV, X0,X1,X2,X3, Y0,Y1,Y2,Y3, lv[0],lv[1],lv[2],lv[3]);
    } else {
        // exact whole-wave fallback (never taken for in-distribution inputs)
        #pragma unroll
        for (int p = 0; p < PPT; ++p) { up[p]=lu[p]=vp[p]=lv[p]=0.f; }
        for (int jj = 0; jj < UNITS; ++jj) {
            const float mxu = mu_u[jj], myu = mu_u[UNITS + jj];
            const float bu_ = beta_u[jj], wu_ = W_u[jj];
            const float mxv = mu_v[jj], myv = mu_v[UNITS + jj];
            const float bv_ = beta_v[jj], wv_ = W_v[jj];
            #pragma unroll
            for (int p = 0; p < PPT; ++p) {
                {
                    const float dx = xs[p] - mxu, dy = ys[p] - myu;
                    const float r2 = fmaf(dx, dx, dy * dy);
                    const float ph = expf(-bu_ * r2);
                    up[p] = fmaf(wu_, ph, up[p]);
                    lu[p] = fmaf(wu_ * ph, fmaf(4.f*bu_*bu_, r2, -4.f*bu_), lu[p]);
                }
                {
                    const float dx = xs[p] - mxv, dy = ys[p] - myv;
                    const float r2 = fmaf(dx, dx, dy * dy);
                    const float ph = expf(-bv_ * r2);
                    vp[p] = fmaf(wv_, ph, vp[p]);
                    lv[p] = fmaf(wv_ * ph, fmaf(4.f*bv_*bv_, r2, -4.f*bv_), lv[p]);
                }
            }
        }
    }

    // ---- residuals ----
    const float dd = p_d[0],  aa = p_a[0], bb = p_b[0];
    const float um = p_um[0], vm = p_vm[0];
    const float us = p_us[0], vs = p_vs[0];
    const float iu  = 1.0f / us, iv = 1.0f / vs;
    const float cau = (aa - um) * iu;
    const float c4b = 4.0f * bb * iu;
    const float cbv = bb * iv;

    float s0 = 0.f, s1 = 0.f, s2 = 0.f, s3 = 0.f, s4 = 0.f, s5 = 0.f;
    #pragma unroll
    for (int p = 0; p < PPT; ++p) {
        const int ii = i0 + p*QSTRIDE;
        const float uu  = gu[ii],  vv  = gv[ii];
        const float ddu = gdu[ii], ddv = gdv[ii];
        float eu = up[p] - uu; s0 += eu * eu;
        float ev = vp[p] - vv; s1 += ev * ev;
        float uph = fmaf(up[p], us, um);
        float vph = fmaf(vp[p], vs, vm);
        float den = fmaf(uph, uph, 1.0f);
        float uvd = uph * vph / den;
        float rpu = fmaf(dd, lu[p], cau) - up[p] - c4b * uvd;
        s2 += rpu * rpu;
        float rdu = lu[p] - ddu; s3 += rdu * rdu;
        float rpv = fmaf(uph, iv, lv[p]) - cbv * uvd;
        s4 += rpv * rpv;
        float rdv = lv[p] - ddv; s5 += rdv * rdv;
    }

    // ---- block reduction (deterministic) ----
    float s[6] = { s0, s1, s2, s3, s4, s5 };
    #pragma unroll
    for (int k = 0; k < 6; ++k) {
        float vsum = s[k];
        for (int off = 32; off > 0; off >>= 1)
            vsum += __shfl_down(vsum, off);
        s[k] = vsum;
    }
    const int lane = tid & 63;
    const int wid  = tid >> 6;
    if (lane == 0) {
        #pragma unroll
        for (int k = 0; k < 6; ++k) red[wid][k] = s[k];
    }
    __syncthreads();
    if (tid < 6) {
        float p = red[0][tid] + red[1][tid] + red[2][tid] + red[3][tid];
        part[tid * MBLK + bid] = p;
    }

    // ---- last-block final reduction (deterministic; R10-proven) ----
    __syncthreads();
    __threadfence();
    if (tid == 0) {
        const unsigned old = atomicAdd(cnt, 1u);
        amLast = (old == MBLK - 1);
    }
    __syncthreads();
    if (amLast) {
        __threadfence();
        float t[6];
        #pragma unroll
        for (int k = 0; k < 6; ++k) {
            float vsum = part[k * MBLK + tid];
            for (int off = 32; off > 0; off >>= 1)
                vsum += __shfl_down(vsum, off);
            t[k] = vsum;
        }
        if (lane == 0) {
            #pragma unroll
            for (int k = 0; k < 6; ++k) red[wid][k] = t[k];
        }
        __syncthreads();
        if (tid == 0) {
            const float inv = 1.0f / (float)NPTS;
            const float Lu  = (red[0][0] + red[1][0] + red[2][0] + red[3][0]) * inv;
            const float Lv  = (red[0][1] + red[1][1] + red[2][1] + red[3][1]) * inv;
            const float Lpu = (red[0][2] + red[1][2] + red[2][2] + red[3][2]) * inv;
            const float Ldu = (red[0][3] + red[1][3] + red[2][3] + red[3][3]) * inv;
            const float Lpv = (red[0][4] + red[1][4] + red[2][4] + red[3][4]) * inv;
            const float Ldv = (red[0][5] + red[1][5] + red[2][5] + red[3][5]) * inv;
            out[0] = 0.1f * Lu + 0.1f * Lv + Lpu + Ldu + Lpv + Ldv;
            out[1] = Lu;
            out[2] = Lpu;
            out[3] = Lv;
            out[4] = Lpv;
            out[5] = Ldu;
            out[6] = Ldv;
        }
    }
}

extern "C" void kernel_launch(void* const* d_in, const int* in_sizes, int n_in,
                              void* d_out, int out_size, void* d_ws, size_t ws_size,
                              hipStream_t stream) {
    const float* gx   = (const float*)d_in[0];
    const float* gy   = (const float*)d_in[1];
    const float* gu   = (const float*)d_in[2];
    const float* gv   = (const float*)d_in[3];
    const float* gdu  = (const float*)d_in[4];
    const float* gdv  = (const float*)d_in[5];
    const float* mu_u = (const float*)d_in[6];
    const float* be_u = (const float*)d_in[7];
    const float* W_u  = (const float*)d_in[8];
    const float* mu_v = (const float*)d_in[9];
    const float* be_v = (const float*)d_in[10];
    const float* W_v  = (const float*)d_in[11];
    const float* p_d  = (const float*)d_in[12];
    const float* p_a  = (const float*)d_in[13];
    const float* p_b  = (const float*)d_in[14];
    const float* p_um = (const float*)d_in[15];
    const float* p_vm = (const float*)d_in[16];
    const float* p_us = (const float*)d_in[17];
    const float* p_vs = (const float*)d_in[18];

    float* wsf     = (float*)d_ws;
    float* partial = wsf;                        // 128*896 = 114688 floats
    float* coefF   = wsf + 114688;               // 896 floats (16B aligned)
    float* part    = wsf + 115584;               // 6*256 floats
    int*   flagBlk = (int*)(wsf + 117120);       // 128 ints
    int*   flagAll = (int*)(wsf + 117248);       // 1 int
    unsigned* cnt  = (unsigned*)(wsf + 117249);  // 1 counter (main)
    float* out     = (float*)d_out;              // 7 floats

    rbf_prep<<<PBLK, 256, 0, stream>>>(mu_u, be_u, W_u, mu_v, be_v, W_v,
                                       partial, flagBlk, cnt);
    rbf_fold<<<4, 256, 0, stream>>>(partial, flagBlk, coefF, flagAll);
    rbf_main<<<MBLK, MTPB, 0, stream>>>(gx, gy, gu, gv, gdu, gdv,
                                        coefF, flagAll,
                                        mu_u, be_u, W_u, mu_v, be_v, W_v,
                                        p_d, p_a, p_b, p_um, p_vm, p_us, p_vs,
                                        part, out, cnt);
}

// Round 20
// 26.635 us; speedup vs baseline: 1.6216x; 1.6216x over previous
//
#include <hip/hip_runtime.h>
#include <hip/hip_bf16.h>
#include <math.h>

#define NPTS   262144
#define UNITS  256
#define STR    15          // rect row stride in prep power-build (deg<=14)
#define NCO    225         // 15*15 rect slots per unit-net build
#define LSTR   16          // padded output row stride (float4-exact)
#define OFF_PU 0           // pred u: rows 0..12 -> 13*16 = 208
#define OFF_LU 208         // lap  u: rows 0..14 -> 15*16 = 240
#define OFF_PV 448
#define OFF_LV 656
#define CFTOT  896         // total padded coefficient floats
#define PBLK   128         // prep blocks (4 waves each, ONE (j,net) per wave)
#define PPT    4           // points per thread in main
#define MTPB   256
#define MBLK   256         // main blocks; MBLK*MTPB*PPT == NPTS
#define QSTRIDE 65536      // point stride between a thread's 4 points

// deg-6 Taylor of e^-t about t=1.1 (monomial coeffs); |err| <= 4e-4 on t in [-0.2,2.4]
__device__ __constant__ float CC[8] = {
    0.99985117f, -0.99903214f, 0.49728235f, -0.16237637f,
    0.03751734f, -0.00582524f, 0.00046232f, 0.0f };

// ---------------------------------------------------------------------------
// prep: wave w of block bid owns task id = bid*4+w -> unit j = id>>1,
// net = id&1 (u-waves: w=0,2 ; v-waves: w=1,3). ONE 7-iteration power-conv
// per wave (half the serial depth of the 2-net version), one staging pass.
// ---------------------------------------------------------------------------
__global__ __launch_bounds__(256) void rbf_prep(
    const float* __restrict__ mu_u, const float* __restrict__ beta_u,
    const float* __restrict__ W_u,
    const float* __restrict__ mu_v, const float* __restrict__ beta_v,
    const float* __restrict__ W_v,
    float* __restrict__ partial, int* __restrict__ flagBlk)
{
    const int tid  = threadIdx.x;
    const int bid  = blockIdx.x;
    const int w    = tid >> 6;
    const int lane = tid & 63;
    const int id   = bid * 4 + w;          // 0..511
    const int j    = id >> 1;              // unit
    const int net  = id & 1;               // 0 = u, 1 = v

    __shared__ float pwA[4][NCO];
    __shared__ float pwB[4][NCO];
    __shared__ int   sflag[4];

    int cidx[4], gi[4], gm[4];
    #pragma unroll
    for (int r = 0; r < 4; ++r) {
        const int c = lane + 64 * r;
        cidx[r] = c;
        gi[r]   = c / STR;
        gm[r]   = c - STR * gi[r];
    }

    const float* mu = net ? mu_v   : mu_u;
    const float* be = net ? beta_v : beta_u;
    const float* W  = net ? W_v    : W_u;
    const float mx  = mu[j], my = mu[UNITS + j];
    const float b   = be[j], wgt = W[j];

    // validity of deg-6 approx over safety box [-0.05,1.05]^2
    const float xlo = -0.05f, xhi = 1.05f;
    const float dxl = xlo - mx, dxh = xhi - mx;
    const float dyl = xlo - my, dyh = xhi - my;
    const float dx2max = fmaxf(dxl*dxl, dxh*dxh);
    const float dy2max = fmaxf(dyl*dyl, dyh*dyh);
    const float dx2min = (dxl <= 0.f && dxh >= 0.f) ? 0.f : fminf(dxl*dxl, dxh*dxh);
    const float dy2min = (dyl <= 0.f && dyh >= 0.f) ? 0.f : fminf(dyl*dyl, dyh*dyh);
    const float t1 = b * (dx2min + dy2min);
    const float t2 = b * (dx2max + dy2max);
    const float tlo = fminf(t1, t2), thi = fmaxf(t1, t2);
    const int bad = !(thi <= 2.4f && tlo >= -0.2f);
    if (lane == 0) sflag[w] = bad;

    // quadratic t(X,Y), X = x-0.5, Y = y-0.5
    const float ax = mx - 0.5f, ay = my - 0.5f;
    const float qXX = b, qYY = b;
    const float qX = -2.f*b*ax, qY = -2.f*b*ay;
    const float q0 = b*(ax*ax + ay*ay);

    const float fourwb = 4.f * wgt * b;
    float cP[8], cL[8];
    #pragma unroll
    for (int m = 0; m < 8; ++m) {
        cP[m] = wgt * CC[m];
        cL[m] = fourwb * ((m ? CC[m-1] : 0.f) - CC[m]);
    }

    float* A = &pwA[w][0];
    float* B = &pwB[w][0];
    #pragma unroll
    for (int r = 0; r < 4; ++r) {
        const int c = cidx[r];
        if (c < NCO) {
            float v = 0.f;
            if (c == 0)          v = q0;
            else if (c == 1)     v = qY;
            else if (c == 2)     v = qYY;
            else if (c == STR)   v = qX;
            else if (c == 2*STR) v = qXX;
            A[c] = v;
        }
    }
    __threadfence_block();

    float aP[4] = {0,0,0,0}, aL[4] = {0,0,0,0};
    #pragma unroll
    for (int r = 0; r < 4; ++r)
        if (cidx[r] == 0) { aP[r] = cP[0]; aL[r] = cL[0]; }

    #pragma unroll
    for (int m = 1; m <= 7; ++m) {
        #pragma unroll
        for (int r = 0; r < 4; ++r) {
            const int c = cidx[r];
            if (c < NCO) {
                const float p = A[c];
                aP[r] = fmaf(cP[m], p, aP[r]);
                aL[r] = fmaf(cL[m], p, aL[r]);
            }
        }
        if (m < 7) {
            #pragma unroll
            for (int r = 0; r < 4; ++r) {
                const int c = cidx[r];
                if (c < NCO) {
                    float acc = q0 * A[c];
                    if (gm[r] >= 1) acc = fmaf(qY,  A[c-1],     acc);
                    if (gm[r] >= 2) acc = fmaf(qYY, A[c-2],     acc);
                    if (gi[r] >= 1) acc = fmaf(qX,  A[c-STR],   acc);
                    if (gi[r] >= 2) acc = fmaf(qXX, A[c-2*STR], acc);
                    B[c] = acc;
                }
            }
            float* T = A; A = B; B = T;
            __threadfence_block();
        }
    }

    // ---- stage per-wave accs, single combined write pass ----
    __syncthreads();
    #pragma unroll
    for (int r = 0; r < 4; ++r) {
        const int c = cidx[r];
        if (c < NCO) { pwA[w][c] = aP[r]; pwB[w][c] = aL[r]; }
    }
    __syncthreads();
    {
        float* dst = partial + bid * CFTOT;
        #pragma unroll
        for (int k = 0; k < 4; ++k) {
            const int c = tid + 256 * k;
            if (c < CFTOT) {
                float v = 0.f;
                int idx, isLap, nsel;
                if (c < 208)      { idx = c;       isLap = 0; nsel = 0; }
                else if (c < 448) { idx = c - 208; isLap = 1; nsel = 0; }
                else if (c < 656) { idx = c - 448; isLap = 0; nsel = 1; }
                else              { idx = c - 656; isLap = 1; nsel = 1; }
                const int i = idx >> 4, m = idx & 15;
                if (m < 15) {
                    const int cs = i * STR + m;
                    if (!isLap) v = pwA[nsel][cs] + pwA[2 + nsel][cs];
                    else        v = pwB[nsel][cs] + pwB[2 + nsel][cs];
                }
                dst[c] = v;
            }
        }
    }
    if (tid == 0)
        flagBlk[bid] = sflag[0] | sflag[1] | sflag[2] | sflag[3];
}

// ---------------------------------------------------------------------------
// fold: 128 block-partials -> coefF (fixed order) + flagAll. 4 blocks.
// ---------------------------------------------------------------------------
__global__ __launch_bounds__(256) void rbf_fold(
    const float* __restrict__ partial, const int* __restrict__ flagBlk,
    float* __restrict__ coefF, int* __restrict__ flagAll)
{
    const int tid = threadIdx.x;
    const int c   = blockIdx.x * 256 + tid;
    if (c < CFTOT) {
        float s = 0.f;
        #pragma unroll 8
        for (int p = 0; p < PBLK; ++p)
            s += partial[p * CFTOT + c];
        coefF[c] = s;
    }
    if (blockIdx.x == 0 && tid < 128) {
        int f = flagBlk[tid];
        for (int off = 32; off > 0; off >>= 1)
            f |= __shfl_down(f, off);
        __shared__ int ff[2];
        if ((tid & 63) == 0) ff[tid >> 6] = f;
        __syncthreads();
        if (tid == 0) *flagAll = ff[0] | ff[1];
    }
}

// ---------------------------------------------------------------------------
// eval4: padded (stride-16) bivariate poly, total degree D, at 4 points.
// One ds_read_b128 (uniform broadcast) feeds 16 FMAs; 4 independent
// Horner chains hide LDS latency at 1 wave/SIMD. (R17-proven)
// ---------------------------------------------------------------------------
template<int D>
__device__ __forceinline__ void eval4(const float* sco,
    float X0, float X1, float X2, float X3,
    float Y0, float Y1, float Y2, float Y3,
    float& h0, float& h1, float& h2, float& h3)
{
    h0 = h1 = h2 = h3 = 0.f;
    #pragma unroll
    for (int ii = 0; ii <= D; ++ii) {
        const int i = D - ii;                 // row, high X-degree first
        const int K = (D - i + 4) / 4;        // quads needed in this row
        float r0 = 0.f, r1 = 0.f, r2 = 0.f, r3 = 0.f;
        #pragma unroll
        for (int kk = 0; kk < K; ++kk) {
            const int k = K - 1 - kk;
            const float4 q = *(const float4*)(sco + i*LSTR + 4*k);
            r0 = fmaf(r0, Y0, q.w); r1 = fmaf(r1, Y1, q.w);
            r2 = fmaf(r2, Y2, q.w); r3 = fmaf(r3, Y3, q.w);
            r0 = fmaf(r0, Y0, q.z); r1 = fmaf(r1, Y1, q.z);
            r2 = fmaf(r2, Y2, q.z); r3 = fmaf(r3, Y3, q.z);
            r0 = fmaf(r0, Y0, q.y); r1 = fmaf(r1, Y1, q.y);
            r2 = fmaf(r2, Y2, q.y); r3 = fmaf(r3, Y3, q.y);
            r0 = fmaf(r0, Y0, q.x); r1 = fmaf(r1, Y1, q.x);
            r2 = fmaf(r2, Y2, q.x); r3 = fmaf(r3, Y3, q.x);
        }
        h0 = fmaf(h0, X0, r0); h1 = fmaf(h1, X1, r1);
        h2 = fmaf(h2, X2, r2); h3 = fmaf(h3, X3, r3);
    }
}

__global__ __launch_bounds__(MTPB) void rbf_main(
    const float* __restrict__ gx, const float* __restrict__ gy,
    const float* __restrict__ gu, const float* __restrict__ gv,
    const float* __restrict__ gdu, const float* __restrict__ gdv,
    const float* __restrict__ coefF, const int* __restrict__ flagAll,
    const float* __restrict__ mu_u, const float* __restrict__ beta_u,
    const float* __restrict__ W_u,
    const float* __restrict__ mu_v, const float* __restrict__ beta_v,
    const float* __restrict__ W_v,
    const float* __restrict__ p_d, const float* __restrict__ p_a,
    const float* __restrict__ p_b, const float* __restrict__ p_um,
    const float* __restrict__ p_vm, const float* __restrict__ p_us,
    const float* __restrict__ p_vs,
    float* __restrict__ part)
{
    const int tid = threadIdx.x;
    const int bid = blockIdx.x;
    const int i0  = bid * MTPB + tid;

    __shared__ __align__(16) float sco[CFTOT];  // 3.6 KB coef table
    if (tid < CFTOT/4)
        ((float4*)sco)[tid] = ((const float4*)coefF)[tid];
    __syncthreads();

    float xs[PPT], ys[PPT];
    #pragma unroll
    for (int p = 0; p < PPT; ++p) {
        xs[p] = gx[i0 + p*QSTRIDE];
        ys[p] = gy[i0 + p*QSTRIDE];
    }

    const int bad = __builtin_amdgcn_readfirstlane(*flagAll);
    bool in = true;
    #pragma unroll
    for (int p = 0; p < PPT; ++p)
        in = in && (xs[p] >= -0.05f) && (xs[p] <= 1.05f)
                && (ys[p] >= -0.05f) && (ys[p] <= 1.05f);
    const bool allIn = __all(in);

    float up[PPT], vp[PPT], lu[PPT], lv[PPT];
    if (!bad && allIn) {
        const float X0 = xs[0]-0.5f, X1 = xs[1]-0.5f, X2 = xs[2]-0.5f, X3 = xs[3]-0.5f;
        const float Y0 = ys[0]-0.5f, Y1 = ys[1]-0.5f, Y2 = ys[2]-0.5f, Y3 = ys[3]-0.5f;
        eval4<12>(sco + OFF_PU, X0,X1,X2,X3, Y0,Y1,Y2,Y3, up[0],up[1],up[2],up[3]);
        eval4<14>(sco + OFF_LU, X0,X1,X2,X3, Y0,Y1,Y2,Y3, lu[0],lu[1],lu[2],lu[3]);
        eval4<12>(sco + OFF_PV, X0,X1,X2,X3, Y0,Y1,Y2,Y3, vp[0],vp[1],vp[2],vp[3]);
        eval4<14>(sco + OFF_LV, X0,X1,X2,X3, Y0,Y1,Y2,Y3, lv[0],lv[1],lv[2],lv[3]);
    } else {
        // exact whole-wave fallback (never taken for in-distribution inputs)
        #pragma unroll
        for (int p = 0; p < PPT; ++p) { up[p]=lu[p]=vp[p]=lv[p]=0.f; }
        for (int jj = 0; jj < UNITS; ++jj) {
            const float mxu = mu_u[jj], myu = mu_u[UNITS + jj];
            const float bu_ = beta_u[jj], wu_ = W_u[jj];
            const float mxv = mu_v[jj], myv = mu_v[UNITS + jj];
            const float bv_ = beta_v[jj], wv_ = W_v[jj];
            #pragma unroll
            for (int p = 0; p < PPT; ++p) {
                {
                    const float dx = xs[p] - mxu, dy = ys[p] - myu;
                    const float r2 = fmaf(dx, dx, dy * dy);
                    const float ph = expf(-bu_ * r2);
                    up[p] = fmaf(wu_, ph, up[p]);
                    lu[p] = fmaf(wu_ * ph, fmaf(4.f*bu_*bu_, r2, -4.f*bu_), lu[p]);
                }
                {
                    const float dx = xs[p] - mxv, dy = ys[p] - myv;
                    const float r2 = fmaf(dx, dx, dy * dy);
                    const float ph = expf(-bv_ * r2);
                    vp[p] = fmaf(wv_, ph, vp[p]);
                    lv[p] = fmaf(wv_ * ph, fmaf(4.f*bv_*bv_, r2, -4.f*bv_), lv[p]);
                }
            }
        }
    }

    // ---- residuals ----
    const float dd = p_d[0],  aa = p_a[0], bb = p_b[0];
    const float um = p_um[0], vm = p_vm[0];
    const float us = p_us[0], vs = p_vs[0];
    const float iu  = 1.0f / us, iv = 1.0f / vs;
    const float cau = (aa - um) * iu;
    const float c4b = 4.0f * bb * iu;
    const float cbv = bb * iv;

    float s0 = 0.f, s1 = 0.f, s2 = 0.f, s3 = 0.f, s4 = 0.f, s5 = 0.f;
    #pragma unroll
    for (int p = 0; p < PPT; ++p) {
        const int ii = i0 + p*QSTRIDE;
        const float uu  = gu[ii],  vv  = gv[ii];
        const float ddu = gdu[ii], ddv = gdv[ii];
        float eu = up[p] - uu; s0 += eu * eu;
        float ev = vp[p] - vv; s1 += ev * ev;
        float uph = fmaf(up[p], us, um);
        float vph = fmaf(vp[p], vs, vm);
        float den = fmaf(uph, uph, 1.0f);
        float uvd = uph * vph / den;
        float rpu = fmaf(dd, lu[p], cau) - up[p] - c4b * uvd;
        s2 += rpu * rpu;
        float rdu = lu[p] - ddu; s3 += rdu * rdu;
        float rpv = fmaf(uph, iv, lv[p]) - cbv * uvd;
        s4 += rpv * rpv;
        float rdv = lv[p] - ddv; s5 += rdv * rdv;
    }

    // ---- block reduction (deterministic) ----
    float s[6] = { s0, s1, s2, s3, s4, s5 };
    __shared__ float red[4][6];
    #pragma unroll
    for (int k = 0; k < 6; ++k) {
        float vsum = s[k];
        for (int off = 32; off > 0; off >>= 1)
            vsum += __shfl_down(vsum, off);
        s[k] = vsum;
    }
    const int lane = tid & 63;
    const int wid  = tid >> 6;
    if (lane == 0) {
        #pragma unroll
        for (int k = 0; k < 6; ++k) red[wid][k] = s[k];
    }
    __syncthreads();
    if (tid < 6) {
        float p = red[0][tid] + red[1][tid] + red[2][tid] + red[3][tid];
        part[tid * MBLK + bid] = p;
    }
}

__global__ __launch_bounds__(256) void rbf_final(
    const float* __restrict__ part, float* __restrict__ out)
{
    const int tid = threadIdx.x;
    __shared__ float red[4][6];
    float s[6];
    #pragma unroll
    for (int k = 0; k < 6; ++k) {
        float vsum = part[k * MBLK + tid];
        for (int off = 32; off > 0; off >>= 1)
            vsum += __shfl_down(vsum, off);
        s[k] = vsum;
    }
    const int lane = tid & 63;
    const int wid  = tid >> 6;
    if (lane == 0) {
        #pragma unroll
        for (int k = 0; k < 6; ++k) red[wid][k] = s[k];
    }
    __syncthreads();
    if (tid == 0) {
        const float inv = 1.0f / (float)NPTS;
        const float Lu  = (red[0][0] + red[1][0] + red[2][0] + red[3][0]) * inv;
        const float Lv  = (red[0][1] + red[1][1] + red[2][1] + red[3][1]) * inv;
        const float Lpu = (red[0][2] + red[1][2] + red[2][2] + red[3][2]) * inv;
        const float Ldu = (red[0][3] + red[1][3] + red[2][3] + red[3][3]) * inv;
        const float Lpv = (red[0][4] + red[1][4] + red[2][4] + red[3][4]) * inv;
        const float Ldv = (red[0][5] + red[1][5] + red[2][5] + red[3][5]) * inv;
        out[0] = 0.1f * Lu + 0.1f * Lv + Lpu + Ldu + Lpv + Ldv;
        out[1] = Lu;
        out[2] = Lpu;
        out[3] = Lv;
        out[4] = Lpv;
        out[5] = Ldu;
        out[6] = Ldv;
    }
}

extern "C" void kernel_launch(void* const* d_in, const int* in_sizes, int n_in,
                              void* d_out, int out_size, void* d_ws, size_t ws_size,
                              hipStream_t stream) {
    const float* gx   = (const float*)d_in[0];
    const float* gy   = (const float*)d_in[1];
    const float* gu   = (const float*)d_in[2];
    const float* gv   = (const float*)d_in[3];
    const float* gdu  = (const float*)d_in[4];
    const float* gdv  = (const float*)d_in[5];
    const float* mu_u = (const float*)d_in[6];
    const float* be_u = (const float*)d_in[7];
    const float* W_u  = (const float*)d_in[8];
    const float* mu_v = (const float*)d_in[9];
    const float* be_v = (const float*)d_in[10];
    const float* W_v  = (const float*)d_in[11];
    const float* p_d  = (const float*)d_in[12];
    const float* p_a  = (const float*)d_in[13];
    const float* p_b  = (const float*)d_in[14];
    const float* p_um = (const float*)d_in[15];
    const float* p_vm = (const float*)d_in[16];
    const float* p_us = (const float*)d_in[17];
    const float* p_vs = (const float*)d_in[18];

    float* wsf     = (float*)d_ws;
    float* partial = wsf;                        // 128*896 = 114688 floats
    float* coefF   = wsf + 114688;               // 896 floats (16B aligned)
    float* part    = wsf + 115584;               // 6*256 floats
    int*   flagBlk = (int*)(wsf + 117120);       // 128 ints
    int*   flagAll = (int*)(wsf + 117248);       // 1 int
    float* out     = (float*)d_out;              // 7 floats

    rbf_prep<<<PBLK, 256, 0, stream>>>(mu_u, be_u, W_u, mu_v, be_v, W_v,
                                       partial, flagBlk);
    rbf_fold<<<4, 256, 0, stream>>>(partial, flagBlk, coefF, flagAll);
    rbf_main<<<MBLK, MTPB, 0, stream>>>(gx, gy, gu, gv, gdu, gdv,
                                        coefF, flagAll,
                                        mu_u, be_u, W_u, mu_v, be_v, W_v,
                                        p_d, p_a, p_b, p_um, p_vm, p_us, p_vs,
                                        part);
    rbf_final<<<1, 256, 0, stream>>>(part, out);
}

// Round 21
// 22.631 us; speedup vs baseline: 1.9085x; 1.1769x over previous
//
#include <hip/hip_runtime.h>
#include <hip/hip_bf16.h>
#include <math.h>

#define NPTS   262144
#define UNITS  256
#define STR    15          // rect row stride in prep power-build (deg<=14)
#define NCO    225         // 15*15 rect slots per unit-net build
#define LSTR   16          // padded output row stride (float4-exact)
#define OFF_PU 0           // pred u: rows 0..12 -> 13*16 = 208
#define OFF_LU 208         // lap  u: rows 0..14 -> 15*16 = 240
#define OFF_PV 448
#define OFF_LV 656
#define CFTOT  896         // total padded coefficient floats (224 float4)
#define PBLK   64          // prep blocks (8 waves each, ONE (j,net) per wave)
#define PTPB   512
#define PPT    4           // points per thread in main
#define MTPB   256
#define MBLK   256         // main blocks; MBLK*MTPB*PPT == NPTS
#define QSTRIDE 65536      // point stride between a thread's 4 points

// deg-6 Taylor of e^-t about t=1.1 (monomial coeffs); |err| <= 4e-4 on t in [-0.2,2.4]
__device__ __constant__ float CC[8] = {
    0.99985117f, -0.99903214f, 0.49728235f, -0.16237637f,
    0.03751734f, -0.00582524f, 0.00046232f, 0.0f };

// ---------------------------------------------------------------------------
// prep: wave w (0..7) of block bid owns task id = bid*8+w -> unit j = id>>1,
// net = id&1 (u-waves even, v-waves odd). ONE 7-iteration power-conv per
// wave; 2 waves/SIMD hide conv latency. One combined staging pass.
// ---------------------------------------------------------------------------
__global__ __launch_bounds__(PTPB) void rbf_prep(
    const float* __restrict__ mu_u, const float* __restrict__ beta_u,
    const float* __restrict__ W_u,
    const float* __restrict__ mu_v, const float* __restrict__ beta_v,
    const float* __restrict__ W_v,
    float* __restrict__ partial, int* __restrict__ flagBlk)
{
    const int tid  = threadIdx.x;
    const int bid  = blockIdx.x;
    const int w    = tid >> 6;             // wave 0..7
    const int lane = tid & 63;
    const int id   = bid * 8 + w;          // 0..511
    const int j    = id >> 1;              // unit
    const int net  = id & 1;               // 0 = u, 1 = v

    __shared__ float pwA[8][NCO];
    __shared__ float pwB[8][NCO];
    __shared__ int   sflag[8];

    int cidx[4], gi[4], gm[4];
    #pragma unroll
    for (int r = 0; r < 4; ++r) {
        const int c = lane + 64 * r;
        cidx[r] = c;
        gi[r]   = c / STR;
        gm[r]   = c - STR * gi[r];
    }

    const float* mu = net ? mu_v   : mu_u;
    const float* be = net ? beta_v : beta_u;
    const float* W  = net ? W_v    : W_u;
    const float mx  = mu[j], my = mu[UNITS + j];
    const float b   = be[j], wgt = W[j];

    // validity of deg-6 approx over safety box [-0.05,1.05]^2
    const float xlo = -0.05f, xhi = 1.05f;
    const float dxl = xlo - mx, dxh = xhi - mx;
    const float dyl = xlo - my, dyh = xhi - my;
    const float dx2max = fmaxf(dxl*dxl, dxh*dxh);
    const float dy2max = fmaxf(dyl*dyl, dyh*dyh);
    const float dx2min = (dxl <= 0.f && dxh >= 0.f) ? 0.f : fminf(dxl*dxl, dxh*dxh);
    const float dy2min = (dyl <= 0.f && dyh >= 0.f) ? 0.f : fminf(dyl*dyl, dyh*dyh);
    const float t1 = b * (dx2min + dy2min);
    const float t2 = b * (dx2max + dy2max);
    const float tlo = fminf(t1, t2), thi = fmaxf(t1, t2);
    const int bad = !(thi <= 2.4f && tlo >= -0.2f);
    if (lane == 0) sflag[w] = bad;

    // quadratic t(X,Y), X = x-0.5, Y = y-0.5
    const float ax = mx - 0.5f, ay = my - 0.5f;
    const float qXX = b, qYY = b;
    const float qX = -2.f*b*ax, qY = -2.f*b*ay;
    const float q0 = b*(ax*ax + ay*ay);

    const float fourwb = 4.f * wgt * b;
    float cP[8], cL[8];
    #pragma unroll
    for (int m = 0; m < 8; ++m) {
        cP[m] = wgt * CC[m];
        cL[m] = fourwb * ((m ? CC[m-1] : 0.f) - CC[m]);
    }

    float* A = &pwA[w][0];
    float* B = &pwB[w][0];
    #pragma unroll
    for (int r = 0; r < 4; ++r) {
        const int c = cidx[r];
        if (c < NCO) {
            float v = 0.f;
            if (c == 0)          v = q0;
            else if (c == 1)     v = qY;
            else if (c == 2)     v = qYY;
            else if (c == STR)   v = qX;
            else if (c == 2*STR) v = qXX;
            A[c] = v;
        }
    }
    __threadfence_block();

    float aP[4] = {0,0,0,0}, aL[4] = {0,0,0,0};
    #pragma unroll
    for (int r = 0; r < 4; ++r)
        if (cidx[r] == 0) { aP[r] = cP[0]; aL[r] = cL[0]; }

    #pragma unroll
    for (int m = 1; m <= 7; ++m) {
        #pragma unroll
        for (int r = 0; r < 4; ++r) {
            const int c = cidx[r];
            if (c < NCO) {
                const float p = A[c];
                aP[r] = fmaf(cP[m], p, aP[r]);
                aL[r] = fmaf(cL[m], p, aL[r]);
            }
        }
        if (m < 7) {
            #pragma unroll
            for (int r = 0; r < 4; ++r) {
                const int c = cidx[r];
                if (c < NCO) {
                    float acc = q0 * A[c];
                    if (gm[r] >= 1) acc = fmaf(qY,  A[c-1],     acc);
                    if (gm[r] >= 2) acc = fmaf(qYY, A[c-2],     acc);
                    if (gi[r] >= 1) acc = fmaf(qX,  A[c-STR],   acc);
                    if (gi[r] >= 2) acc = fmaf(qXX, A[c-2*STR], acc);
                    B[c] = acc;
                }
            }
            float* T = A; A = B; B = T;
            __threadfence_block();
        }
    }

    // ---- stage per-wave accs, single combined write pass ----
    __syncthreads();
    #pragma unroll
    for (int r = 0; r < 4; ++r) {
        const int c = cidx[r];
        if (c < NCO) { pwA[w][c] = aP[r]; pwB[w][c] = aL[r]; }
    }
    __syncthreads();
    {
        float* dst = partial + bid * CFTOT;
        #pragma unroll
        for (int k = 0; k < 2; ++k) {
            const int c = tid + PTPB * k;
            if (c < CFTOT) {
                float v = 0.f;
                int idx, isLap, nsel;
                if (c < 208)      { idx = c;       isLap = 0; nsel = 0; }
                else if (c < 448) { idx = c - 208; isLap = 1; nsel = 0; }
                else if (c < 656) { idx = c - 448; isLap = 0; nsel = 1; }
                else              { idx = c - 656; isLap = 1; nsel = 1; }
                const int i = idx >> 4, m = idx & 15;
                if (m < 15) {
                    const int cs = i * STR + m;
                    if (!isLap)
                        v = (pwA[nsel][cs]     + pwA[nsel + 2][cs]) +
                            (pwA[nsel + 4][cs] + pwA[nsel + 6][cs]);
                    else
                        v = (pwB[nsel][cs]     + pwB[nsel + 2][cs]) +
                            (pwB[nsel + 4][cs] + pwB[nsel + 6][cs]);
                }
                dst[c] = v;
            }
        }
    }
    if (tid == 0)
        flagBlk[bid] = sflag[0] | sflag[1] | sflag[2] | sflag[3] |
                       sflag[4] | sflag[5] | sflag[6] | sflag[7];
}

// ---------------------------------------------------------------------------
// eval4: padded (stride-16) bivariate poly, total degree D, at 4 points.
// One ds_read_b128 (uniform broadcast) feeds 16 FMAs; 4 independent
// Horner chains hide LDS latency at 1 wave/SIMD. (R17-proven)
// ---------------------------------------------------------------------------
template<int D>
__device__ __forceinline__ void eval4(const float* sco,
    float X0, float X1, float X2, float X3,
    float Y0, float Y1, float Y2, float Y3,
    float& h0, float& h1, float& h2, float& h3)
{
    h0 = h1 = h2 = h3 = 0.f;
    #pragma unroll
    for (int ii = 0; ii <= D; ++ii) {
        const int i = D - ii;                 // row, high X-degree first
        const int K = (D - i + 4) / 4;        // quads needed in this row
        float r0 = 0.f, r1 = 0.f, r2 = 0.f, r3 = 0.f;
        #pragma unroll
        for (int kk = 0; kk < K; ++kk) {
            const int k = K - 1 - kk;
            const float4 q = *(const float4*)(sco + i*LSTR + 4*k);
            r0 = fmaf(r0, Y0, q.w); r1 = fmaf(r1, Y1, q.w);
            r2 = fmaf(r2, Y2, q.w); r3 = fmaf(r3, Y3, q.w);
            r0 = fmaf(r0, Y0, q.z); r1 = fmaf(r1, Y1, q.z);
            r2 = fmaf(r2, Y2, q.z); r3 = fmaf(r3, Y3, q.z);
            r0 = fmaf(r0, Y0, q.y); r1 = fmaf(r1, Y1, q.y);
            r2 = fmaf(r2, Y2, q.y); r3 = fmaf(r3, Y3, q.y);
            r0 = fmaf(r0, Y0, q.x); r1 = fmaf(r1, Y1, q.x);
            r2 = fmaf(r2, Y2, q.x); r3 = fmaf(r3, Y3, q.x);
        }
        h0 = fmaf(h0, X0, r0); h1 = fmaf(h1, X1, r1);
        h2 = fmaf(h2, X2, r2); h3 = fmaf(h3, X3, r3);
    }
}

__global__ __launch_bounds__(MTPB) void rbf_main(
    const float* __restrict__ gx, const float* __restrict__ gy,
    const float* __restrict__ gu, const float* __restrict__ gv,
    const float* __restrict__ gdu, const float* __restrict__ gdv,
    const float* __restrict__ partial, const int* __restrict__ flagBlk,
    const float* __restrict__ mu_u, const float* __restrict__ beta_u,
    const float* __restrict__ W_u,
    const float* __restrict__ mu_v, const float* __restrict__ beta_v,
    const float* __restrict__ W_v,
    const float* __restrict__ p_d, const float* __restrict__ p_a,
    const float* __restrict__ p_b, const float* __restrict__ p_um,
    const float* __restrict__ p_vm, const float* __restrict__ p_us,
    const float* __restrict__ p_vs,
    float* __restrict__ part)
{
    const int tid = threadIdx.x;
    const int bid = blockIdx.x;
    const int i0  = bid * MTPB + tid;

    __shared__ __align__(16) float sco[CFTOT];  // 3.6 KB coef table
    __shared__ int sbad;

    // inline fixed-order fold of the 64 block-partials (L2-hot, ~0.3 us)
    if (tid < CFTOT/4) {
        const float4* P4 = (const float4*)partial;
        float4 acc = {0.f, 0.f, 0.f, 0.f};
        #pragma unroll 8
        for (int p = 0; p < PBLK; ++p) {
            const float4 q = P4[p * (CFTOT/4) + tid];
            acc.x += q.x; acc.y += q.y; acc.z += q.z; acc.w += q.w;
        }
        ((float4*)sco)[tid] = acc;
    }
    if (tid < 64) {
        int f = (tid < PBLK) ? flagBlk[tid] : 0;
        for (int off = 32; off > 0; off >>= 1)
            f |= __shfl_down(f, off);
        if (tid == 0) sbad = f;
    }
    __syncthreads();

    float xs[PPT], ys[PPT];
    #pragma unroll
    for (int p = 0; p < PPT; ++p) {
        xs[p] = gx[i0 + p*QSTRIDE];
        ys[p] = gy[i0 + p*QSTRIDE];
    }

    const int bad = __builtin_amdgcn_readfirstlane(sbad);
    bool in = true;
    #pragma unroll
    for (int p = 0; p < PPT; ++p)
        in = in && (xs[p] >= -0.05f) && (xs[p] <= 1.05f)
                && (ys[p] >= -0.05f) && (ys[p] <= 1.05f);
    const bool allIn = __all(in);

    float up[PPT], vp[PPT], lu[PPT], lv[PPT];
    if (!bad && allIn) {
        const float X0 = xs[0]-0.5f, X1 = xs[1]-0.5f, X2 = xs[2]-0.5f, X3 = xs[3]-0.5f;
        const float Y0 = ys[0]-0.5f, Y1 = ys[1]-0.5f, Y2 = ys[2]-0.5f, Y3 = ys[3]-0.5f;
        eval4<12>(sco + OFF_PU, X0,X1,X2,X3, Y0,Y1,Y2,Y3, up[0],up[1],up[2],up[3]);
        eval4<14>(sco + OFF_LU, X0,X1,X2,X3, Y0,Y1,Y2,Y3, lu[0],lu[1],lu[2],lu[3]);
        eval4<12>(sco + OFF_PV, X0,X1,X2,X3, Y0,Y1,Y2,Y3, vp[0],vp[1],vp[2],vp[3]);
        eval4<14>(sco + OFF_LV, X0,X1,X2,X3, Y0,Y1,Y2,Y3, lv[0],lv[1],lv[2],lv[3]);
    } else {
        // exact whole-wave fallback (never taken for in-distribution inputs)
        #pragma unroll
        for (int p = 0; p < PPT; ++p) { up[p]=lu[p]=vp[p]=lv[p]=0.f; }
        for (int jj = 0; jj < UNITS; ++jj) {
            const float mxu = mu_u[jj], myu = mu_u[UNITS + jj];
            const float bu_ = beta_u[jj], wu_ = W_u[jj];
            const float mxv = mu_v[jj], myv = mu_v[UNITS + jj];
            const float bv_ = beta_v[jj], wv_ = W_v[jj];
            #pragma unroll
            for (int p = 0; p < PPT; ++p) {
                {
                    const float dx = xs[p] - mxu, dy = ys[p] - myu;
                    const float r2 = fmaf(dx, dx, dy * dy);
                    const float ph = expf(-bu_ * r2);
                    up[p] = fmaf(wu_, ph, up[p]);
                    lu[p] = fmaf(wu_ * ph, fmaf(4.f*bu_*bu_, r2, -4.f*bu_), lu[p]);
                }
                {
                    const float dx = xs[p] - mxv, dy = ys[p] - myv;
                    const float r2 = fmaf(dx, dx, dy * dy);
                    const float ph = expf(-bv_ * r2);
                    vp[p] = fmaf(wv_, ph, vp[p]);
                    lv[p] = fmaf(wv_ * ph, fmaf(4.f*bv_*bv_, r2, -4.f*bv_), lv[p]);
                }
            }
        }
    }

    // ---- residuals ----
    const float dd = p_d[0],  aa = p_a[0], bb = p_b[0];
    const float um = p_um[0], vm = p_vm[0];
    const float us = p_us[0], vs = p_vs[0];
    const float iu  = 1.0f / us, iv = 1.0f / vs;
    const float cau = (aa - um) * iu;
    const float c4b = 4.0f * bb * iu;
    const float cbv = bb * iv;

    float s0 = 0.f, s1 = 0.f, s2 = 0.f, s3 = 0.f, s4 = 0.f, s5 = 0.f;
    #pragma unroll
    for (int p = 0; p < PPT; ++p) {
        const int ii = i0 + p*QSTRIDE;
        const float uu  = gu[ii],  vv  = gv[ii];
        const float ddu = gdu[ii], ddv = gdv[ii];
        float eu = up[p] - uu; s0 += eu * eu;
        float ev = vp[p] - vv; s1 += ev * ev;
        float uph = fmaf(up[p], us, um);
        float vph = fmaf(vp[p], vs, vm);
        float den = fmaf(uph, uph, 1.0f);
        float uvd = uph * vph / den;
        float rpu = fmaf(dd, lu[p], cau) - up[p] - c4b * uvd;
        s2 += rpu * rpu;
        float rdu = lu[p] - ddu; s3 += rdu * rdu;
        float rpv = fmaf(uph, iv, lv[p]) - cbv * uvd;
        s4 += rpv * rpv;
        float rdv = lv[p] - ddv; s5 += rdv * rdv;
    }

    // ---- block reduction (deterministic) ----
    float s[6] = { s0, s1, s2, s3, s4, s5 };
    __shared__ float red[4][6];
    #pragma unroll
    for (int k = 0; k < 6; ++k) {
        float vsum = s[k];
        for (int off = 32; off > 0; off >>= 1)
            vsum += __shfl_down(vsum, off);
        s[k] = vsum;
    }
    const int lane = tid & 63;
    const int wid  = tid >> 6;
    if (lane == 0) {
        #pragma unroll
        for (int k = 0; k < 6; ++k) red[wid][k] = s[k];
    }
    __syncthreads();
    if (tid < 6) {
        float p = red[0][tid] + red[1][tid] + red[2][tid] + red[3][tid];
        part[tid * MBLK + bid] = p;
    }
}

__global__ __launch_bounds__(256) void rbf_final(
    const float* __restrict__ part, float* __restrict__ out)
{
    const int tid = threadIdx.x;
    __shared__ float red[4][6];
    float s[6];
    #pragma unroll
    for (int k = 0; k < 6; ++k) {
        float vsum = part[k * MBLK + tid];
        for (int off = 32; off > 0; off >>= 1)
            vsum += __shfl_down(vsum, off);
        s[k] = vsum;
    }
    const int lane = tid & 63;
    const int wid  = tid >> 6;
    if (lane == 0) {
        #pragma unroll
        for (int k = 0; k < 6; ++k) red[wid][k] = s[k];
    }
    __syncthreads();
    if (tid == 0) {
        const float inv = 1.0f / (float)NPTS;
        const float Lu  = (red[0][0] + red[1][0] + red[2][0] + red[3][0]) * inv;
        const float Lv  = (red[0][1] + red[1][1] + red[2][1] + red[3][1]) * inv;
        const float Lpu = (red[0][2] + red[1][2] + red[2][2] + red[3][2]) * inv;
        const float Ldu = (red[0][3] + red[1][3] + red[2][3] + red[3][3]) * inv;
        const float Lpv = (red[0][4] + red[1][4] + red[2][4] + red[3][4]) * inv;
        const float Ldv = (red[0][5] + red[1][5] + red[2][5] + red[3][5]) * inv;
        out[0] = 0.1f * Lu + 0.1f * Lv + Lpu + Ldu + Lpv + Ldv;
        out[1] = Lu;
        out[2] = Lpu;
        out[3] = Lv;
        out[4] = Lpv;
        out[5] = Ldu;
        out[6] = Ldv;
    }
}

extern "C" void kernel_launch(void* const* d_in, const int* in_sizes, int n_in,
                              void* d_out, int out_size, void* d_ws, size_t ws_size,
                              hipStream_t stream) {
    const float* gx   = (const float*)d_in[0];
    const float* gy   = (const float*)d_in[1];
    const float* gu   = (const float*)d_in[2];
    const float* gv   = (const float*)d_in[3];
    const float* gdu  = (const float*)d_in[4];
    const float* gdv  = (const float*)d_in[5];
    const float* mu_u = (const float*)d_in[6];
    const float* be_u = (const float*)d_in[7];
    const float* W_u  = (const float*)d_in[8];
    const float* mu_v = (const float*)d_in[9];
    const float* be_v = (const float*)d_in[10];
    const float* W_v  = (const float*)d_in[11];
    const float* p_d  = (const float*)d_in[12];
    const float* p_a  = (const float*)d_in[13];
    const float* p_b  = (const float*)d_in[14];
    const float* p_um = (const float*)d_in[15];
    const float* p_vm = (const float*)d_in[16];
    const float* p_us = (const float*)d_in[17];
    const float* p_vs = (const float*)d_in[18];

    float* wsf     = (float*)d_ws;
    float* partial = wsf;                        // 64*896 = 57344 floats
    float* part    = wsf + 57344;                // 6*256 floats
    int*   flagBlk = (int*)(wsf + 58880);        // 64 ints
    float* out     = (float*)d_out;              // 7 floats

    rbf_prep<<<PBLK, PTPB, 0, stream>>>(mu_u, be_u, W_u, mu_v, be_v, W_v,
                                        partial, flagBlk);
    rbf_main<<<MBLK, MTPB, 0, stream>>>(gx, gy, gu, gv, gdu, gdv,
                                        partial, flagBlk,
                                        mu_u, be_u, W_u, mu_v, be_v, W_v,
                                        p_d, p_a, p_b, p_um, p_vm, p_us, p_vs,
                                        part);
    rbf_final<<<1, 256, 0, stream>>>(part, out);
}